// Round 3
// baseline (5209.168 us; speedup 1.0000x reference)
//
#include <hip/hip_runtime.h>
#include <hip/hip_cooperative_groups.h>
#include <stdint.h>

namespace cg = cooperative_groups;

// ---------------- problem constants ----------------
constexpr int TT = 128;    // time steps
constexpr int BB = 256;    // batch
constexpr int LL = 1024;   // hidden dim
constexpr int NG = 4096;   // 4 gates * LL
constexpr int VV = 95;     // vocab

typedef short bf16x8 __attribute__((ext_vector_type(8)));
typedef float f32x4  __attribute__((ext_vector_type(4)));

__device__ __forceinline__ unsigned short f2bf(float f) {
    unsigned int u = __builtin_bit_cast(unsigned int, f);
    unsigned int r = (u + 0x7FFFu + ((u >> 16) & 1u)) >> 16;
    return (unsigned short)r;
}
__device__ __forceinline__ float bf2f(unsigned short h) {
    unsigned int u = ((unsigned int)h) << 16;
    return __builtin_bit_cast(float, u);
}
__device__ __forceinline__ float sigmoidf_(float x) {
    return 1.0f / (1.0f + __expf(-x));
}
__device__ __forceinline__ float tanhf_(float x) {
    return 1.0f - 2.0f / (__expf(2.0f * x) + 1.0f);
}

// ---------------- prep: split W into Wperm (recurrent, bf16) + Wemb hi/lo (bf16 pair) ----
// Global n-row ordering (everywhere): row = lt*64 + gate*16 + li, l = lt*16 + li.
__global__ void prep_w_all(const float* __restrict__ Wf, const float* __restrict__ Wi,
                           const float* __restrict__ Wo, const float* __restrict__ Wc,
                           unsigned short* __restrict__ Wperm,
                           unsigned short* __restrict__ Wemb_hi,
                           unsigned short* __restrict__ Wemb_lo) {
    int idx = blockIdx.x * 256 + threadIdx.x;
    const int total = NG * 2048;  // 8M
    for (; idx < total; idx += gridDim.x * 256) {
        int row = idx >> 11;        // 0..4095
        int col = idx & 2047;       // 0..2047
        int lt   = row >> 6;
        int nl   = row & 63;
        int gate = nl >> 4;
        int l    = lt * 16 + (nl & 15);
        const float* W = (gate == 0) ? Wf : (gate == 1) ? Wi : (gate == 2) ? Wo : Wc;
        float w = W[l * 2048 + col];
        if (col >= 1024) {
            Wperm[row * 1024 + (col - 1024)] = f2bf(w);
        } else {
            unsigned short hi = f2bf(w);
            float lo = w - bf2f(hi);
            Wemb_hi[row * 1024 + col] = hi;
            Wemb_lo[row * 1024 + col] = f2bf(lo);
        }
    }
}

// ---------------- prep: emb hi/lo split, padded to 96 rows ----------------
__global__ void prep_emb_split(const float* __restrict__ emb,
                               unsigned short* __restrict__ Eh,
                               unsigned short* __restrict__ El) {
    int idx = blockIdx.x * 256 + threadIdx.x;   // 96*1024 = 98304 threads exactly
    int v = idx >> 10;
    float w = (v < VV) ? emb[idx] : 0.0f;
    unsigned short hi = f2bf(w);
    Eh[idx] = hi;
    El[idx] = f2bf(w - bf2f(hi));
}

// ---------------- prep: gate_pre2[v][l][gate] = emb[v] . Wemb_row + bias  (MFMA hi/lo) ----
// grid 64 blocks (lt), 128 threads (2 waves). Wave wm: rows wm*48..wm*48+47 (3 m-frags).
__global__ __launch_bounds__(128)
void gate_pre_mfma(const unsigned short* __restrict__ Eh, const unsigned short* __restrict__ El,
                   const unsigned short* __restrict__ Wh, const unsigned short* __restrict__ Wl,
                   const float* __restrict__ bfv, const float* __restrict__ biv,
                   const float* __restrict__ bov, const float* __restrict__ bcv,
                   float* __restrict__ gp2) {
    const int lt   = blockIdx.x;
    const int tid  = threadIdx.x;
    const int lane = tid & 63;
    const int wm   = tid >> 6;
    const int l15  = lane & 15;
    const int kq   = lane >> 4;          // 0..3

    f32x4 acc[3][4];
    #pragma unroll
    for (int mf = 0; mf < 3; ++mf)
        #pragma unroll
        for (int nf = 0; nf < 4; ++nf) acc[mf][nf] = (f32x4){0.f, 0.f, 0.f, 0.f};

    #pragma unroll 2
    for (int ks = 0; ks < 32; ++ks) {
        const int k0 = ks * 32 + kq * 8;
        bf16x8 ah[3], al[3], bh[4], bl[4];
        #pragma unroll
        for (int mf = 0; mf < 3; ++mf) {
            const size_t ao = (size_t)(wm * 48 + mf * 16 + l15) * 1024 + k0;
            ah[mf] = *(const bf16x8*)(Eh + ao);
            al[mf] = *(const bf16x8*)(El + ao);
        }
        #pragma unroll
        for (int nf = 0; nf < 4; ++nf) {
            const size_t bo = (size_t)(lt * 64 + nf * 16 + l15) * 1024 + k0;
            bh[nf] = *(const bf16x8*)(Wh + bo);
            bl[nf] = *(const bf16x8*)(Wl + bo);
        }
        #pragma unroll
        for (int mf = 0; mf < 3; ++mf)
            #pragma unroll
            for (int nf = 0; nf < 4; ++nf) {
                acc[mf][nf] = __builtin_amdgcn_mfma_f32_16x16x32_bf16(ah[mf], bh[nf], acc[mf][nf], 0, 0, 0);
                acc[mf][nf] = __builtin_amdgcn_mfma_f32_16x16x32_bf16(ah[mf], bl[nf], acc[mf][nf], 0, 0, 0);
                acc[mf][nf] = __builtin_amdgcn_mfma_f32_16x16x32_bf16(al[mf], bh[nf], acc[mf][nf], 0, 0, 0);
            }
    }

    const int lgl = lt * 16 + l15;
    #pragma unroll
    for (int nf = 0; nf < 4; ++nf) {
        const float* bias = (nf == 0) ? bfv : (nf == 1) ? biv : (nf == 2) ? bov : bcv;
        const float bv = bias[lgl];
        #pragma unroll
        for (int mf = 0; mf < 3; ++mf)
            #pragma unroll
            for (int r = 0; r < 4; ++r) {
                const int v = wm * 48 + mf * 16 + kq * 4 + r;   // C/D row = (lane>>4)*4 + r
                if (v < VV)
                    gp2[((size_t)v * LL + lgl) * 4 + nf] = acc[mf][nf][r] + bv;
            }
    }
}

// ---------------- prep: init h0 (bf16) ----------------
__global__ void init_state(const float* __restrict__ h_init, unsigned short* __restrict__ h0) {
    int idx = blockIdx.x * 256 + threadIdx.x;   // 1024*256 = 262144 = BB*LL
    h0[idx] = f2bf(h_init[idx]);
}

// ---------------- persistent LSTM: all 128 steps, W resident in LDS ----------------
// grid 256 blocks (bt=blk>>6, lt=blk&63), 128 threads (2 waves of 32 batch rows each).
// c lives in registers for the whole sequence. No barriers in the K-loop.
__global__ __launch_bounds__(128, 1)
void lstm_persist(const unsigned short* __restrict__ Wperm,
                  const float* __restrict__ gp2,
                  const int* __restrict__ x,
                  unsigned short* __restrict__ hb0,
                  unsigned short* __restrict__ hb1,
                  float* __restrict__ out) {
    __shared__ unsigned short wlds_s[64 * 1024];   // 128 KiB
    char* wlds = (char*)wlds_s;

    const int tid  = threadIdx.x;
    const int lane = tid & 63;
    const int wm   = tid >> 6;
    const int blk  = blockIdx.x;
    const int bt   = blk >> 6;
    const int lt   = blk & 63;

    // --- load W slice (64 n-rows x 1024 k) into LDS, XOR-swizzled for conflict-free b128 reads
    {
        const char* wg = (const char*)(Wperm + (size_t)lt * 64 * 1024);
        #pragma unroll 4
        for (int i = 0; i < 64; ++i) {
            const int idx = i * 128 + tid;
            const int byteoff = idx * 16;
            const int n  = byteoff >> 11;
            const int kb = byteoff & 2047;
            uint4 v = *(const uint4*)(wg + byteoff);
            *(uint4*)(wlds + n * 2048 + (kb ^ ((n & 7) << 4))) = v;
        }
    }
    __syncthreads();

    cg::grid_group grid = cg::this_grid();

    const int l15 = lane & 15;
    const int kq  = lane >> 4;                // 0..3
    const int xm  = (l15 & 7) << 4;           // swizzle mask (bits 4-6)

    int bbase[4];
    #pragma unroll
    for (int nf = 0; nf < 4; ++nf) bbase[nf] = (nf * 16 + l15) * 2048;

    // A row byte offsets into h buffers (row stride 2048 B)
    const size_t arow0 = (size_t)(bt * 64 + wm * 32 + l15) * 2048 + kq * 16;
    const size_t arow1 = arow0 + 16 * 2048;
    const size_t lcol  = (size_t)(lt * 16 + l15);

    float c[2][4] = {{0.f, 0.f, 0.f, 0.f}, {0.f, 0.f, 0.f, 0.f}};

    for (int t = 0; t < TT; ++t) {
        const char* hin  = (const char*)((t & 1) ? hb1 : hb0);
        char*       hout = (char*)((t & 1) ? hb0 : hb1);

        f32x4 acc[2][4];
        #pragma unroll
        for (int mf = 0; mf < 2; ++mf)
            #pragma unroll
            for (int nf = 0; nf < 4; ++nf) acc[mf][nf] = (f32x4){0.f, 0.f, 0.f, 0.f};

        #pragma unroll 8
        for (int ks = 0; ks < 32; ++ks) {
            const bf16x8 a0 = *(const bf16x8*)(hin + arow0 + ks * 64);
            const bf16x8 a1 = *(const bf16x8*)(hin + arow1 + ks * 64);
            const int kb = ks * 64 + kq * 16;
            const bf16x8 b0 = *(const bf16x8*)(wlds + bbase[0] + (kb ^ xm));
            const bf16x8 b1 = *(const bf16x8*)(wlds + bbase[1] + (kb ^ xm));
            const bf16x8 b2 = *(const bf16x8*)(wlds + bbase[2] + (kb ^ xm));
            const bf16x8 b3 = *(const bf16x8*)(wlds + bbase[3] + (kb ^ xm));
            acc[0][0] = __builtin_amdgcn_mfma_f32_16x16x32_bf16(a0, b0, acc[0][0], 0, 0, 0);
            acc[0][1] = __builtin_amdgcn_mfma_f32_16x16x32_bf16(a0, b1, acc[0][1], 0, 0, 0);
            acc[0][2] = __builtin_amdgcn_mfma_f32_16x16x32_bf16(a0, b2, acc[0][2], 0, 0, 0);
            acc[0][3] = __builtin_amdgcn_mfma_f32_16x16x32_bf16(a0, b3, acc[0][3], 0, 0, 0);
            acc[1][0] = __builtin_amdgcn_mfma_f32_16x16x32_bf16(a1, b0, acc[1][0], 0, 0, 0);
            acc[1][1] = __builtin_amdgcn_mfma_f32_16x16x32_bf16(a1, b1, acc[1][1], 0, 0, 0);
            acc[1][2] = __builtin_amdgcn_mfma_f32_16x16x32_bf16(a1, b2, acc[1][2], 0, 0, 0);
            acc[1][3] = __builtin_amdgcn_mfma_f32_16x16x32_bf16(a1, b3, acc[1][3], 0, 0, 0);
        }

        // epilogue: lane owns (b, l) for 8 rows; nf = gate (f,i,o,c~)
        const int* xt = x + t * BB;
        float* out_t = out + (size_t)t * BB * LL;
        #pragma unroll
        for (int mf = 0; mf < 2; ++mf) {
            #pragma unroll
            for (int r = 0; r < 4; ++r) {
                const int b = bt * 64 + wm * 32 + mf * 16 + kq * 4 + r;
                const int v = xt[b];
                const float4 gp = *(const float4*)(gp2 + ((size_t)v * LL + lcol) * 4);
                const float gf = acc[mf][0][r] + gp.x;
                const float gi = acc[mf][1][r] + gp.y;
                const float go = acc[mf][2][r] + gp.z;
                const float gc = acc[mf][3][r] + gp.w;
                const float cn = sigmoidf_(gf) * c[mf][r] + sigmoidf_(gi) * tanhf_(gc);
                const float hn = sigmoidf_(go) * tanhf_(cn);
                c[mf][r] = cn;
                const size_t off = (size_t)b * LL + lcol;
                out_t[off] = hn;
                *(unsigned short*)(hout + off * 2) = f2bf(hn);
            }
        }
        grid.sync();
    }
}

// ---------------- launch ----------------
extern "C" void kernel_launch(void* const* d_in, const int* in_sizes, int n_in,
                              void* d_out, int out_size, void* d_ws, size_t ws_size,
                              hipStream_t stream) {
    const int*   x      = (const int*)d_in[0];
    const float* h_init = (const float*)d_in[1];
    const float* emb    = (const float*)d_in[2];
    const float* Wf     = (const float*)d_in[3];
    const float* bfv    = (const float*)d_in[4];
    const float* Wi     = (const float*)d_in[5];
    const float* biv    = (const float*)d_in[6];
    const float* Wo     = (const float*)d_in[7];
    const float* bov    = (const float*)d_in[8];
    const float* Wc     = (const float*)d_in[9];
    const float* bcv    = (const float*)d_in[10];
    float* out = (float*)d_out;

    char* ws = (char*)d_ws;
    unsigned short* Wperm   = (unsigned short*)(ws);                 // 8 MB
    unsigned short* Wemb_hi = (unsigned short*)(ws + 8388608);       // 8 MB
    unsigned short* Wemb_lo = (unsigned short*)(ws + 16777216);      // 8 MB
    unsigned short* Eh      = (unsigned short*)(ws + 25165824);      // 192 KB
    unsigned short* El      = (unsigned short*)(ws + 25362432);      // 192 KB
    float*          gp2     = (float*)(ws + 25559040);               // 1.5 MB (96 rows)
    unsigned short* hb0     = (unsigned short*)(ws + 27131904);      // 512 KB
    unsigned short* hb1     = (unsigned short*)(ws + 27656192);      // 512 KB

    prep_w_all<<<4096, 256, 0, stream>>>(Wf, Wi, Wo, Wc, Wperm, Wemb_hi, Wemb_lo);
    prep_emb_split<<<384, 256, 0, stream>>>(emb, Eh, El);
    gate_pre_mfma<<<64, 128, 0, stream>>>(Eh, El, Wemb_hi, Wemb_lo,
                                          bfv, biv, bov, bcv, gp2);
    init_state<<<1024, 256, 0, stream>>>(h_init, hb0);

    void* kargs[] = {(void*)&Wperm, (void*)&gp2, (void*)&x,
                     (void*)&hb0, (void*)&hb1, (void*)&out};
    hipLaunchCooperativeKernel(reinterpret_cast<void*>(lstm_persist),
                               dim3(256), dim3(128), kargs, 0, stream);
}

// Round 4
// 1252.824 us; speedup vs baseline: 4.1579x; 4.1579x over previous
//
#include <hip/hip_runtime.h>
#include <stdint.h>

// ---------------- problem constants ----------------
constexpr int TT = 128;    // time steps
constexpr int BB = 256;    // batch
constexpr int LL = 1024;   // hidden dim
constexpr int NG = 4096;   // 4 gates * LL
constexpr int VV = 95;     // vocab

typedef short bf16x8 __attribute__((ext_vector_type(8)));
typedef float f32x4  __attribute__((ext_vector_type(4)));

typedef __attribute__((address_space(1))) const uint32_t gu32;
typedef __attribute__((address_space(3))) uint32_t lu32;

__device__ __forceinline__ unsigned short f2bf(float f) {
    unsigned int u = __builtin_bit_cast(unsigned int, f);
    unsigned int r = (u + 0x7FFFu + ((u >> 16) & 1u)) >> 16;
    return (unsigned short)r;
}
__device__ __forceinline__ float bf2f(unsigned short h) {
    unsigned int u = ((unsigned int)h) << 16;
    return __builtin_bit_cast(float, u);
}
__device__ __forceinline__ float sigmoidf_(float x) {
    return 1.0f / (1.0f + __expf(-x));
}
__device__ __forceinline__ float tanhf_(float x) {
    return 1.0f - 2.0f / (__expf(2.0f * x) + 1.0f);
}

// ---------------- prep: W split ----------------
// Recurrent half -> Wimg, an LDS-image per lt-slice (131072 B):
//   slice lt, chunk j=k>>5 (0..31, 4096B each), row nl (0..63, 64B each), byte (k&31)*2.
// Embedding half -> Wemb hi/lo (row-major [row][k], row = lt*64 + gate*16 + li).
__global__ void prep_w_all(const float* __restrict__ Wf, const float* __restrict__ Wi,
                           const float* __restrict__ Wo, const float* __restrict__ Wc,
                           unsigned short* __restrict__ Wimg,
                           unsigned short* __restrict__ Wemb_hi,
                           unsigned short* __restrict__ Wemb_lo) {
    int idx = blockIdx.x * 256 + threadIdx.x;
    const int total = NG * 2048;  // 8M
    for (; idx < total; idx += gridDim.x * 256) {
        int row = idx >> 11;        // 0..4095
        int col = idx & 2047;       // 0..2047
        int lt   = row >> 6;
        int nl   = row & 63;
        int gate = nl >> 4;
        int l    = lt * 16 + (nl & 15);
        const float* W = (gate == 0) ? Wf : (gate == 1) ? Wi : (gate == 2) ? Wo : Wc;
        float w = W[l * 2048 + col];
        if (col >= 1024) {
            int k = col - 1024;
            size_t byte = (size_t)lt * 131072 + (size_t)(k >> 5) * 4096 + nl * 64 + (k & 31) * 2;
            *(unsigned short*)((char*)Wimg + byte) = f2bf(w);
        } else {
            unsigned short hi = f2bf(w);
            float lo = w - bf2f(hi);
            Wemb_hi[row * 1024 + col] = hi;
            Wemb_lo[row * 1024 + col] = f2bf(lo);
        }
    }
}

// ---------------- prep: emb hi/lo split, padded to 96 rows ----------------
__global__ void prep_emb_split(const float* __restrict__ emb,
                               unsigned short* __restrict__ Eh,
                               unsigned short* __restrict__ El) {
    int idx = blockIdx.x * 256 + threadIdx.x;   // 96*1024 threads
    int v = idx >> 10;
    float w = (v < VV) ? emb[idx] : 0.0f;
    unsigned short hi = f2bf(w);
    Eh[idx] = hi;
    El[idx] = f2bf(w - bf2f(hi));
}

// ---------------- prep: gate_pre2[v][l][gate] via hi/lo MFMA ----------------
__global__ __launch_bounds__(128)
void gate_pre_mfma(const unsigned short* __restrict__ Eh, const unsigned short* __restrict__ El,
                   const unsigned short* __restrict__ Wh, const unsigned short* __restrict__ Wl,
                   const float* __restrict__ bfv, const float* __restrict__ biv,
                   const float* __restrict__ bov, const float* __restrict__ bcv,
                   float* __restrict__ gp2) {
    const int lt   = blockIdx.x;
    const int tid  = threadIdx.x;
    const int lane = tid & 63;
    const int wm   = tid >> 6;
    const int l15  = lane & 15;
    const int kq   = lane >> 4;          // 0..3

    f32x4 acc[3][4];
    #pragma unroll
    for (int mf = 0; mf < 3; ++mf)
        #pragma unroll
        for (int nf = 0; nf < 4; ++nf) acc[mf][nf] = (f32x4){0.f, 0.f, 0.f, 0.f};

    #pragma unroll 2
    for (int ks = 0; ks < 32; ++ks) {
        const int k0 = ks * 32 + kq * 8;
        bf16x8 ah[3], al[3], bh[4], bl[4];
        #pragma unroll
        for (int mf = 0; mf < 3; ++mf) {
            const size_t ao = (size_t)(wm * 48 + mf * 16 + l15) * 1024 + k0;
            ah[mf] = *(const bf16x8*)(Eh + ao);
            al[mf] = *(const bf16x8*)(El + ao);
        }
        #pragma unroll
        for (int nf = 0; nf < 4; ++nf) {
            const size_t bo = (size_t)(lt * 64 + nf * 16 + l15) * 1024 + k0;
            bh[nf] = *(const bf16x8*)(Wh + bo);
            bl[nf] = *(const bf16x8*)(Wl + bo);
        }
        #pragma unroll
        for (int mf = 0; mf < 3; ++mf)
            #pragma unroll
            for (int nf = 0; nf < 4; ++nf) {
                acc[mf][nf] = __builtin_amdgcn_mfma_f32_16x16x32_bf16(ah[mf], bh[nf], acc[mf][nf], 0, 0, 0);
                acc[mf][nf] = __builtin_amdgcn_mfma_f32_16x16x32_bf16(ah[mf], bl[nf], acc[mf][nf], 0, 0, 0);
                acc[mf][nf] = __builtin_amdgcn_mfma_f32_16x16x32_bf16(al[mf], bh[nf], acc[mf][nf], 0, 0, 0);
            }
    }

    const int lgl = lt * 16 + l15;
    #pragma unroll
    for (int nf = 0; nf < 4; ++nf) {
        const float* bias = (nf == 0) ? bfv : (nf == 1) ? biv : (nf == 2) ? bov : bcv;
        const float bv = bias[lgl];
        #pragma unroll
        for (int mf = 0; mf < 3; ++mf)
            #pragma unroll
            for (int r = 0; r < 4; ++r) {
                const int v = wm * 48 + mf * 16 + kq * 4 + r;
                if (v < VV)
                    gp2[((size_t)v * LL + lgl) * 4 + nf] = acc[mf][nf][r] + bv;
            }
    }
}

// ---------------- prep: init h0 (bf16) and c (=0) ----------------
__global__ void init_state(const float* __restrict__ h_init,
                           unsigned short* __restrict__ h0, float* __restrict__ c) {
    int idx = blockIdx.x * 256 + threadIdx.x;   // 1024*256 = BB*LL
    h0[idx] = f2bf(h_init[idx]);
    c[idx] = 0.f;
}

// ---------------- per-timestep kernel ----------------
// grid 256 (bt=blk>>6, lt=blk&63), 256 threads = 4 waves, wave w: m-rows w*16..w*16+15.
// B staged via global_load_lds (chunk-interleaved image, conflict-free), counted vmcnt,
// A direct global->reg double-buffered per quarter. 1 barrier per quarter only.
__global__ __launch_bounds__(256, 1)
void lstm_step2(const unsigned short* __restrict__ Wimg,
                const float* __restrict__ gp2,
                const int* __restrict__ x_t,
                const unsigned short* __restrict__ h_in,
                unsigned short* __restrict__ h_out,
                float* __restrict__ c_ws,
                float* __restrict__ out_t) {
    __shared__ unsigned short wlds_s[65536];   // 128 KiB
    char* wlds = (char*)wlds_s;

    const int tid  = threadIdx.x;
    const int lane = tid & 63;
    const int wv   = tid >> 6;
    const int bt   = blockIdx.x >> 6;
    const int lt   = blockIdx.x & 63;
    const int l15  = lane & 15;
    const int kq   = lane >> 4;

    // ---- issue all 32 B-stage loads (1 KB per wave-instr, linear LDS dest) ----
    const char* wsrc = (const char*)Wimg + (size_t)lt * 131072 + tid * 16;
    #pragma unroll
    for (int j = 0; j < 32; ++j) {
        __builtin_amdgcn_global_load_lds((gu32*)(wsrc + j * 4096),
                                         (lu32*)(wlds + j * 4096 + wv * 1024),
                                         16, 0, 0);
    }

    // A: wave w reads rows bt*64 + w*16 + l15, byte k-offset = ks*64 + kq*16
    const char* aptr = (const char*)h_in + (size_t)(bt * 64 + wv * 16 + l15) * 2048 + kq * 16;
    // B frag base: chunk ks at ks*4096, row (nf*16+l15)*64, lane k-slot kq*16
    const char* bbase = wlds + l15 * 64 + kq * 16;

    f32x4 acc[4];
    #pragma unroll
    for (int nf = 0; nf < 4; ++nf) acc[nf] = (f32x4){0.f, 0.f, 0.f, 0.f};

    bf16x8 aA[8], aB[8];

    #define LOAD_A(dst, qq)                                                  \
        _Pragma("unroll") for (int ki = 0; ki < 8; ++ki)                     \
            dst[ki] = *(const bf16x8*)(aptr + ((qq) * 8 + ki) * 64);

    #define QCOMP(areg, qq)                                                  \
        _Pragma("unroll") for (int ki = 0; ki < 8; ++ki) {                   \
            const int ks = (qq) * 8 + ki;                                    \
            const char* bc = bbase + ks * 4096;                              \
            bf16x8 b0 = *(const bf16x8*)(bc);                                \
            bf16x8 b1 = *(const bf16x8*)(bc + 1024);                         \
            bf16x8 b2 = *(const bf16x8*)(bc + 2048);                         \
            bf16x8 b3 = *(const bf16x8*)(bc + 3072);                         \
            acc[0] = __builtin_amdgcn_mfma_f32_16x16x32_bf16(areg[ki], b0, acc[0], 0, 0, 0); \
            acc[1] = __builtin_amdgcn_mfma_f32_16x16x32_bf16(areg[ki], b1, acc[1], 0, 0, 0); \
            acc[2] = __builtin_amdgcn_mfma_f32_16x16x32_bf16(areg[ki], b2, acc[2], 0, 0, 0); \
            acc[3] = __builtin_amdgcn_mfma_f32_16x16x32_bf16(areg[ki], b3, acc[3], 0, 0, 0); \
        }

    #define QWAIT()                                                          \
        asm volatile("s_waitcnt vmcnt(32)" ::: "memory");                    \
        __builtin_amdgcn_s_barrier();

    LOAD_A(aA, 0)
    QWAIT()            // S0..7 staged (32 = 24 newer stages + 8 A-batch0)
    LOAD_A(aB, 1)
    QCOMP(aA, 0)
    QWAIT()            // issued 48 -> >=16 complete -> S0..15
    LOAD_A(aA, 2)
    QCOMP(aB, 1)
    QWAIT()            // issued 56 -> >=24 complete -> S0..23
    LOAD_A(aB, 3)
    QCOMP(aA, 2)
    QWAIT()            // issued 64 -> >=32 complete -> all staged
    QCOMP(aB, 3)

    #undef LOAD_A
    #undef QCOMP
    #undef QWAIT

    // ---- epilogue: lane owns (b, l); acc[nf] = gates f,i,o,c~ ----
    const int l = lt * 16 + l15;
    #pragma unroll
    for (int r = 0; r < 4; ++r) {
        const int b = bt * 64 + wv * 16 + kq * 4 + r;
        const int v = x_t[b];
        const float4 gp = *(const float4*)(gp2 + ((size_t)v * LL + l) * 4);
        const float gf = acc[0][r] + gp.x;
        const float gi = acc[1][r] + gp.y;
        const float go = acc[2][r] + gp.z;
        const float gc = acc[3][r] + gp.w;
        const size_t off = (size_t)b * LL + l;
        const float cold = c_ws[off];
        const float cn = sigmoidf_(gf) * cold + sigmoidf_(gi) * tanhf_(gc);
        const float hn = sigmoidf_(go) * tanhf_(cn);
        c_ws[off] = cn;
        out_t[off] = hn;
        h_out[off] = f2bf(hn);
    }
}

// ---------------- launch ----------------
extern "C" void kernel_launch(void* const* d_in, const int* in_sizes, int n_in,
                              void* d_out, int out_size, void* d_ws, size_t ws_size,
                              hipStream_t stream) {
    const int*   x      = (const int*)d_in[0];
    const float* h_init = (const float*)d_in[1];
    const float* emb    = (const float*)d_in[2];
    const float* Wf     = (const float*)d_in[3];
    const float* bfv    = (const float*)d_in[4];
    const float* Wi     = (const float*)d_in[5];
    const float* biv    = (const float*)d_in[6];
    const float* Wo     = (const float*)d_in[7];
    const float* bov    = (const float*)d_in[8];
    const float* Wc     = (const float*)d_in[9];
    const float* bcv    = (const float*)d_in[10];
    float* out = (float*)d_out;

    char* ws = (char*)d_ws;
    unsigned short* Wimg    = (unsigned short*)(ws);                 // 8 MB
    unsigned short* Wemb_hi = (unsigned short*)(ws + 8388608);       // 8 MB
    unsigned short* Wemb_lo = (unsigned short*)(ws + 16777216);      // 8 MB
    unsigned short* Eh      = (unsigned short*)(ws + 25165824);      // 192 KB
    unsigned short* El      = (unsigned short*)(ws + 25362432);      // 192 KB
    float*          gp2     = (float*)(ws + 25559040);               // 1.5 MB
    float*          c_ws    = (float*)(ws + 27131904);               // 1 MB
    unsigned short* hb0     = (unsigned short*)(ws + 28180480);      // 512 KB
    unsigned short* hb1     = (unsigned short*)(ws + 28704768);      // 512 KB

    prep_w_all<<<4096, 256, 0, stream>>>(Wf, Wi, Wo, Wc, Wimg, Wemb_hi, Wemb_lo);
    prep_emb_split<<<384, 256, 0, stream>>>(emb, Eh, El);
    gate_pre_mfma<<<64, 128, 0, stream>>>(Eh, El, Wemb_hi, Wemb_lo,
                                          bfv, biv, bov, bcv, gp2);
    init_state<<<1024, 256, 0, stream>>>(h_init, hb0, c_ws);

    unsigned short* hin = hb0;
    unsigned short* hout = hb1;
    for (int t = 0; t < TT; ++t) {
        lstm_step2<<<256, 256, 0, stream>>>(Wimg, gp2, x + t * BB,
                                            hin, hout, c_ws,
                                            out + (size_t)t * BB * LL);
        unsigned short* tmp = hin; hin = hout; hout = tmp;
    }
}